// Round 7
// baseline (556.472 us; speedup 1.0000x reference)
//
#include <hip/hip_runtime.h>
#include <math.h>

#define NN 100000
#define NE 1000000
#define CAP 32        // bucket capacity per node; degrees ~Poisson(10), max ~27
#define OVCAP 4096    // overflow list capacity (correct fallback, ~never used)
#define NWIN 489      // ceil(NE / 2048) edge windows
#define NBUCK (NWIN * 8)   // bucket blocks: 8 region-blocks per window
#define NGEMM 1024
#define REGDIV 12500  // dst region = dst / 12500  -> 0..7
// H = 64 channels, hard-coded throughout.

// ---- monotonic float<->uint encoding for atomicMax on floats ----
__device__ __forceinline__ unsigned fenc(float f) {
  unsigned u = __float_as_uint(f);
  return (u & 0x80000000u) ? ~u : (u | 0x80000000u);
}
__device__ __forceinline__ float fdec(unsigned u) {
  return (u & 0x80000000u) ? __uint_as_float(u & 0x7fffffffu)
                           : __uint_as_float(~u);
}

// ---------------- fused: XCD-partitioned bucket build + GEMM1 ----------------
// Blocks [0, NBUCK): bucket edges by dst, but each block only handles dsts in
// its region (blockIdx&7). Consecutive blockIdx round-robin XCDs, so each
// XCD's L2 only dirties its own 3.2MB bucket slice -> single writeback per
// line instead of ~6 (R6: WRITE_SIZE 62MB for 8MB of stores).
// Blocks [NBUCK, NBUCK+NGEMM): Y = X @ W1 (independent work, fills the VALU
// while bucket blocks sit in atomic/store latency).

__global__ __launch_bounds__(256) void k_bucket_gemm(const int* __restrict__ src,
                                                     const int* __restrict__ dst,
                                                     const float* __restrict__ ew,
                                                     int* __restrict__ cnt,
                                                     int2* __restrict__ bucket,
                                                     int4* __restrict__ ovf,
                                                     int* __restrict__ ovf_n,
                                                     const float* __restrict__ X,
                                                     const float* __restrict__ W,
                                                     float* __restrict__ Y) {
  int bid = blockIdx.x;
  if (bid < NBUCK) {
    int region = bid & 7;
    int base = (bid >> 3) * 2048;
#pragma unroll
    for (int it = 0; it < 8; ++it) {
      int e = base + it * 256 + threadIdx.x;
      if (e < NE) {
        int d = dst[e];
        if (d / REGDIV == region) {
          int s = src[e];
          float w = ew[e];
          int pos = atomicAdd(&cnt[d], 1);
          if (pos < CAP) {
            bucket[d * CAP + pos] = make_int2(s, __float_as_int(w));
          } else {
            int t = atomicAdd(ovf_n, 1);
            if (t < OVCAP) ovf[t] = make_int4(s, d, __float_as_int(w), 0);
          }
        }
      }
    }
  } else {
    int lane = threadIdx.x & 63;
    int wid = (bid - NBUCK) * 4 + (threadIdx.x >> 6);
    int nw = NGEMM * 4;
    float wcol[64];
#pragma unroll
    for (int k = 0; k < 64; ++k) wcol[k] = W[k * 64 + lane];
    for (int node = wid; node < NN; node += nw) {
      float xv = X[node * 64 + lane];
      float acc = 0.0f;
#pragma unroll
      for (int k = 0; k < 64; ++k) {
        float xb = __int_as_float(__builtin_amdgcn_readlane(__float_as_int(xv), k));
        acc = fmaf(xb, wcol[k], acc);
      }
      Y[node * 64 + lane] = acc;
    }
  }
}

// ---------------- weighted degree (no atomics): sum own bucket + self-loop ----------------

__global__ __launch_bounds__(256) void k_degsum(const int* __restrict__ cnt,
                                                const int2* __restrict__ bucket,
                                                const int4* __restrict__ ovf,
                                                const int* __restrict__ ovf_n,
                                                float* __restrict__ dinv) {
  int i = blockIdx.x * 256 + threadIdx.x;
  if (i >= NN) return;
  int c = cnt[i];
  int cc = c < CAP ? c : CAP;
  float dsum = 1.0f;  // self-loop weight
  const int2* bk = bucket + (size_t)i * CAP;
  for (int j = 0; j < cc; ++j) dsum += __int_as_float(bk[j].y);
  if (c > CAP) {
    int on = ovf_n[0]; if (on > OVCAP) on = OVCAP;
    for (int t = 0; t < on; ++t) {
      int4 o = ovf[t];
      if (o.y == i) dsum += __int_as_float(o.z);
    }
  }
  dinv[i] = 1.0f / sqrtf(dsum);  // dsum >= 1 always
}

// ---------------- 64x64 GEMM: Y[N,64] = X[N,64] @ W[64,64] ----------------

__global__ __launch_bounds__(256) void k_gemm64(const float* __restrict__ X,
                                                const float* __restrict__ W,
                                                float* __restrict__ Y) {
  int lane = threadIdx.x & 63;
  int wid = blockIdx.x * 4 + (threadIdx.x >> 6);
  int nw = gridDim.x * 4;
  float wcol[64];
#pragma unroll
  for (int k = 0; k < 64; ++k) wcol[k] = W[k * 64 + lane];
  for (int node = wid; node < NN; node += nw) {
    float xv = X[node * 64 + lane];
    float acc = 0.0f;
#pragma unroll
    for (int k = 0; k < 64; ++k) {
      float xb = __int_as_float(__builtin_amdgcn_readlane(__float_as_int(xv), k));
      acc = fmaf(xb, wcol[k], acc);
    }
    Y[node * 64 + lane] = acc;
  }
}

// ---------------- vectorized gather core (see R6) ----------------
// Lane split: eg = lane>>4 (edge slot), cq = lane&15 (channel quad).
// Returns float4 acc valid in ALL lanes.

__device__ __forceinline__ float4 gather_row(const float* __restrict__ xw,
                                             const float* __restrict__ dinv,
                                             const int* __restrict__ cnt,
                                             const int2* __restrict__ bucket,
                                             const int4* __restrict__ ovf,
                                             const int* __restrict__ ovf_n,
                                             int node, int eg, int cq, float di) {
  int c = cnt[node];
  int cc = c < CAP ? c : CAP;
  const int2* bk = bucket + (size_t)node * CAP;
  float4 acc = make_float4(0.f, 0.f, 0.f, 0.f);

  int e0 = 0;
  for (; e0 + 8 <= cc; e0 += 8) {
    int2 Ea = bk[e0 + eg];
    int2 Eb = bk[e0 + 4 + eg];
    const float4 xa = *(const float4*)(xw + (size_t)Ea.x * 64 + cq * 4);
    const float4 xb = *(const float4*)(xw + (size_t)Eb.x * 64 + cq * 4);
    float va = dinv[Ea.x] * __int_as_float(Ea.y) * di;
    float vb = dinv[Eb.x] * __int_as_float(Eb.y) * di;
    acc.x = fmaf(xa.x, va, acc.x); acc.y = fmaf(xa.y, va, acc.y);
    acc.z = fmaf(xa.z, va, acc.z); acc.w = fmaf(xa.w, va, acc.w);
    acc.x = fmaf(xb.x, vb, acc.x); acc.y = fmaf(xb.y, vb, acc.y);
    acc.z = fmaf(xb.z, vb, acc.z); acc.w = fmaf(xb.w, vb, acc.w);
  }
  for (; e0 < cc; e0 += 4) {
    int e = e0 + eg;
    if (e < cc) {
      int2 E = bk[e];
      const float4 xa = *(const float4*)(xw + (size_t)E.x * 64 + cq * 4);
      float v = dinv[E.x] * __int_as_float(E.y) * di;
      acc.x = fmaf(xa.x, v, acc.x); acc.y = fmaf(xa.y, v, acc.y);
      acc.z = fmaf(xa.z, v, acc.z); acc.w = fmaf(xa.w, v, acc.w);
    }
  }
  acc.x += __shfl_xor(acc.x, 16, 64); acc.y += __shfl_xor(acc.y, 16, 64);
  acc.z += __shfl_xor(acc.z, 16, 64); acc.w += __shfl_xor(acc.w, 16, 64);
  acc.x += __shfl_xor(acc.x, 32, 64); acc.y += __shfl_xor(acc.y, 32, 64);
  acc.z += __shfl_xor(acc.z, 32, 64); acc.w += __shfl_xor(acc.w, 32, 64);

  if (c > CAP) {
    int on = ovf_n[0]; if (on > OVCAP) on = OVCAP;
    for (int t = 0; t < on; ++t) {
      int4 o = ovf[t];
      if (o.y == node) {
        const float4 xa = *(const float4*)(xw + (size_t)o.x * 64 + cq * 4);
        float v = dinv[o.x] * __int_as_float(o.z) * di;
        acc.x = fmaf(xa.x, v, acc.x); acc.y = fmaf(xa.y, v, acc.y);
        acc.z = fmaf(xa.z, v, acc.z); acc.w = fmaf(xa.w, v, acc.w);
      }
    }
  }
  const float4 xs = *(const float4*)(xw + (size_t)node * 64 + cq * 4);
  float dd = di * di;
  acc.x = fmaf(xs.x, dd, acc.x); acc.y = fmaf(xs.y, dd, acc.y);
  acc.z = fmaf(xs.z, dd, acc.z); acc.w = fmaf(xs.w, dd, acc.w);
  return acc;
}

// ---------------- layer-1 aggregation: gather + bias + ReLU ----------------

__global__ __launch_bounds__(256) void k_gather_l1(const float* __restrict__ xw,
                                                   const float* __restrict__ dinv,
                                                   const int* __restrict__ cnt,
                                                   const int2* __restrict__ bucket,
                                                   const int4* __restrict__ ovf,
                                                   const int* __restrict__ ovf_n,
                                                   const float* __restrict__ b,
                                                   float* __restrict__ h) {
  int lane = threadIdx.x & 63;
  int node = blockIdx.x * 4 + (threadIdx.x >> 6);
  if (node >= NN) return;
  int eg = lane >> 4, cq = lane & 15;
  float di = dinv[node];
  float4 acc = gather_row(xw, dinv, cnt, bucket, ovf, ovf_n, node, eg, cq, di);
  const float4 b4 = *(const float4*)(b + cq * 4);
  float4 r;
  r.x = fmaxf(acc.x + b4.x, 0.f); r.y = fmaxf(acc.y + b4.y, 0.f);
  r.z = fmaxf(acc.z + b4.z, 0.f); r.w = fmaxf(acc.w + b4.w, 0.f);
  if (lane < 16) *(float4*)(h + (size_t)node * 64 + cq * 4) = r;
}

// ---------------- layer-2 aggregation fused with heads + global-max epilogue ----------------
// NN % 4 == 0, so every block has 4 valid nodes (safe to use __syncthreads).

__global__ __launch_bounds__(256) void k_gather_l2_heads(const float* __restrict__ xw,
                                                         const float* __restrict__ dinv,
                                                         const int* __restrict__ cnt,
                                                         const int2* __restrict__ bucket,
                                                         const int4* __restrict__ ovf,
                                                         const int* __restrict__ ovf_n,
                                                         const float* __restrict__ b2,
                                                         const float* __restrict__ Wn,
                                                         const float* __restrict__ bn,
                                                         const float* __restrict__ Wr,
                                                         const float* __restrict__ br,
                                                         float* __restrict__ logits,
                                                         float* __restrict__ rr,
                                                         unsigned* __restrict__ gmax_u) {
  __shared__ unsigned smax[4];
  int lane = threadIdx.x & 63;
  int wv = threadIdx.x >> 6;
  int node = blockIdx.x * 4 + wv;
  int eg = lane >> 4, cq = lane & 15;
  float di = dinv[node];
  float4 acc = gather_row(xw, dinv, cnt, bucket, ovf, ovf_n, node, eg, cq, di);
  const float4 b4 = *(const float4*)(b2 + cq * 4);
  float4 r;
  r.x = fmaxf(acc.x + b4.x, 0.f); r.y = fmaxf(acc.y + b4.y, 0.f);
  r.z = fmaxf(acc.z + b4.z, 0.f); r.w = fmaxf(acc.w + b4.w, 0.f);
  const float4 wn4 = *(const float4*)(Wn + cq * 4);
  const float4 wr4 = *(const float4*)(Wr + cq * 4);
  float an = r.x * wn4.x + r.y * wn4.y + r.z * wn4.z + r.w * wn4.w;
  float ar = r.x * wr4.x + r.y * wr4.y + r.z * wr4.z + r.w * wr4.w;
#pragma unroll
  for (int m = 8; m > 0; m >>= 1) {
    an += __shfl_xor(an, m, 64);
    ar += __shfl_xor(ar, m, 64);
  }
  float lg = an + bn[0];
  if (lane == 0) {
    logits[node] = lg;
    float xr = ar + br[0];
    rr[node] = 0.01f / (1.0f + expf(-xr));
    smax[wv] = fenc(lg);
  }
  __syncthreads();
  if (threadIdx.x == 0) {
    unsigned m0 = smax[0] > smax[1] ? smax[0] : smax[1];
    unsigned m1 = smax[2] > smax[3] ? smax[2] : smax[3];
    unsigned m = m0 > m1 ? m0 : m1;
    atomicMax(gmax_u, m);  // order-independent -> deterministic
  }
}

// ---------------- softmax: exp + atomic global sum, then normalize ----------------

#define RB 256  // reduction grid

__global__ __launch_bounds__(256) void k_sexp(const float* __restrict__ logits,
                                              const unsigned* __restrict__ gmax_u,
                                              float* __restrict__ sel,
                                              float* __restrict__ gsum) {
  __shared__ float s[256];
  float m = fdec(gmax_u[0]);
  float acc = 0.0f;
  for (int i = blockIdx.x * 256 + threadIdx.x; i < NN; i += RB * 256) {
    float e = expf(logits[i] - m);
    sel[i] = e;
    acc += e;
  }
  s[threadIdx.x] = acc;
  __syncthreads();
  for (int w = 128; w > 0; w >>= 1) {
    if (threadIdx.x < w) s[threadIdx.x] += s[threadIdx.x + w];
    __syncthreads();
  }
  if (threadIdx.x == 0) unsafeAtomicAdd(gsum, s[0]);
}

__global__ __launch_bounds__(256) void k_snorm(float* __restrict__ sel,
                                               const float* __restrict__ gsum) {
  int i = blockIdx.x * 256 + threadIdx.x;
  if (i < NN) sel[i] *= (1.0f / gsum[0]);
}

// ---------------- launch ----------------

extern "C" void kernel_launch(void* const* d_in, const int* in_sizes, int n_in,
                              void* d_out, int out_size, void* d_ws, size_t ws_size,
                              hipStream_t stream) {
  const float* x  = (const float*)d_in[0];
  const int*   ei = (const int*)d_in[1];   // [2, E]: src row then dst row
  const float* ew = (const float*)d_in[2];
  const float* W1 = (const float*)d_in[3];
  const float* b1 = (const float*)d_in[4];
  const float* W2 = (const float*)d_in[5];
  const float* b2 = (const float*)d_in[6];
  const float* Wn = (const float*)d_in[7];
  const float* bn = (const float*)d_in[8];
  const float* Wr = (const float*)d_in[9];
  const float* br = (const float*)d_in[10];
  const int* src = ei;
  const int* dst = ei + NE;

  // ws layout (word offsets keep float4/int2/int4 regions 16B-aligned).
  // cnt, ovf_n, gmax_u, gsum are CONSECUTIVE so one memset zeroes all.
  float* ws = (float*)d_ws;
  float* xw      = ws;                                 // NN*64
  float* h       = xw + (size_t)NN * 64;               // NN*64
  float* dinv    = h + (size_t)NN * 64;                // NN
  float* logits  = dinv + NN;                          // NN
  int2*  bucket  = (int2*)(logits + NN);               // NN*CAP int2
  int*   cnt     = (int*)(bucket + (size_t)NN * CAP);  // NN
  int*   ovf_n   = cnt + NN;                           // 1
  unsigned* gmax_u = (unsigned*)(ovf_n + 1);           // 1
  float* gsum    = (float*)(gmax_u + 1);               // 1
  int4*  ovf     = (int4*)(gsum + 1);                  // OVCAP int4 (16B-aligned: offset is multiple of 4 words)

  float* sel = (float*)d_out;                          // node_selector [N]
  float* rr  = (float*)d_out + NN;                     // rescue_ratios [N]

  int gN  = (NN + 255) / 256;
  int gN4 = NN / 4;  // NN % 4 == 0

  // ---- zero cnt + ovf_n + gmax_u + gsum in one memset ----
  hipMemsetAsync(cnt, 0, (size_t)(NN + 3) * 4, stream);

  // ---- bucket build (XCD-partitioned) + GEMM1, co-scheduled ----
  k_bucket_gemm<<<NBUCK + NGEMM, 256, 0, stream>>>(src, dst, ew, cnt, bucket,
                                                   ovf, ovf_n, x, W1, xw);
  k_degsum<<<gN, 256, 0, stream>>>(cnt, bucket, ovf, ovf_n, dinv);

  // ---- layer 1 aggregation ----
  k_gather_l1<<<gN4, 256, 0, stream>>>(xw, dinv, cnt, bucket, ovf, ovf_n, b1, h);

  // ---- layer 2: gemm -> gather fused with heads (+global max) ----
  k_gemm64<<<1024, 256, 0, stream>>>(h, W2, xw);
  k_gather_l2_heads<<<gN4, 256, 0, stream>>>(xw, dinv, cnt, bucket, ovf, ovf_n,
                                             b2, Wn, bn, Wr, br, logits, rr, gmax_u);

  // ---- softmax: exp+sum, normalize ----
  k_sexp<<<RB, 256, 0, stream>>>(logits, gmax_u, sel, gsum);
  k_snorm<<<gN, 256, 0, stream>>>(sel, gsum);
}

// Round 8
// 320.368 us; speedup vs baseline: 1.7370x; 1.7370x over previous
//
#include <hip/hip_runtime.h>
#include <math.h>

#define NN 100000
#define NE 1000000
#define CAP 32        // bucket capacity per node; degrees ~Poisson(10), max ~27
#define OVCAP 4096    // overflow list capacity (correct fallback, ~never used)
#define NWIN 489      // ceil(NE / 2048) edge windows
#define NBUCK (NWIN * 8)   // bucket blocks: 8 region-blocks per window
#define NGEMM 1024
#define REGDIV 12500  // dst region = dst / 12500  -> 0..7
// H = 64 channels, hard-coded throughout.

// ---------------- fused: XCD-partitioned bucket build + GEMM1 ----------------
// Blocks [0, NBUCK): bucket edges by dst; each block handles only dsts in its
// region (blockIdx&7) so each XCD's L2 dirties only its own bucket slice.
// Blocks [NBUCK, ...): Y = X @ W1 co-scheduled under the bucket latency.

__global__ __launch_bounds__(256) void k_bucket_gemm(const int* __restrict__ src,
                                                     const int* __restrict__ dst,
                                                     const float* __restrict__ ew,
                                                     int* __restrict__ cnt,
                                                     int2* __restrict__ bucket,
                                                     int4* __restrict__ ovf,
                                                     int* __restrict__ ovf_n,
                                                     const float* __restrict__ X,
                                                     const float* __restrict__ W,
                                                     float* __restrict__ Y) {
  int bid = blockIdx.x;
  if (bid < NBUCK) {
    int region = bid & 7;
    int base = (bid >> 3) * 2048;
#pragma unroll
    for (int it = 0; it < 8; ++it) {
      int e = base + it * 256 + threadIdx.x;
      if (e < NE) {
        int d = dst[e];
        if (d / REGDIV == region) {
          int s = src[e];
          float w = ew[e];
          int pos = atomicAdd(&cnt[d], 1);
          if (pos < CAP) {
            bucket[d * CAP + pos] = make_int2(s, __float_as_int(w));
          } else {
            int t = atomicAdd(ovf_n, 1);
            if (t < OVCAP) ovf[t] = make_int4(s, d, __float_as_int(w), 0);
          }
        }
      }
    }
  } else {
    int lane = threadIdx.x & 63;
    int wid = (bid - NBUCK) * 4 + (threadIdx.x >> 6);
    int nw = NGEMM * 4;
    float wcol[64];
#pragma unroll
    for (int k = 0; k < 64; ++k) wcol[k] = W[k * 64 + lane];
    for (int node = wid; node < NN; node += nw) {
      float xv = X[node * 64 + lane];
      float acc = 0.0f;
#pragma unroll
      for (int k = 0; k < 64; ++k) {
        float xb = __int_as_float(__builtin_amdgcn_readlane(__float_as_int(xv), k));
        acc = fmaf(xb, wcol[k], acc);
      }
      Y[node * 64 + lane] = acc;
    }
  }
}

// ---------------- weighted degree (no atomics): sum own bucket + self-loop ----------------

__global__ __launch_bounds__(256) void k_degsum(const int* __restrict__ cnt,
                                                const int2* __restrict__ bucket,
                                                const int4* __restrict__ ovf,
                                                const int* __restrict__ ovf_n,
                                                float* __restrict__ dinv) {
  int i = blockIdx.x * 256 + threadIdx.x;
  if (i >= NN) return;
  int c = cnt[i];
  int cc = c < CAP ? c : CAP;
  float dsum = 1.0f;  // self-loop weight
  const int2* bk = bucket + (size_t)i * CAP;
  for (int j = 0; j < cc; ++j) dsum += __int_as_float(bk[j].y);
  if (c > CAP) {
    int on = ovf_n[0]; if (on > OVCAP) on = OVCAP;
    for (int t = 0; t < on; ++t) {
      int4 o = ovf[t];
      if (o.y == i) dsum += __int_as_float(o.z);
    }
  }
  dinv[i] = 1.0f / sqrtf(dsum);  // dsum >= 1 always
}

// ---------------- 64x64 GEMM: Y[N,64] = X[N,64] @ W[64,64] ----------------

__global__ __launch_bounds__(256) void k_gemm64(const float* __restrict__ X,
                                                const float* __restrict__ W,
                                                float* __restrict__ Y) {
  int lane = threadIdx.x & 63;
  int wid = blockIdx.x * 4 + (threadIdx.x >> 6);
  int nw = gridDim.x * 4;
  float wcol[64];
#pragma unroll
  for (int k = 0; k < 64; ++k) wcol[k] = W[k * 64 + lane];
  for (int node = wid; node < NN; node += nw) {
    float xv = X[node * 64 + lane];
    float acc = 0.0f;
#pragma unroll
    for (int k = 0; k < 64; ++k) {
      float xb = __int_as_float(__builtin_amdgcn_readlane(__float_as_int(xv), k));
      acc = fmaf(xb, wcol[k], acc);
    }
    Y[node * 64 + lane] = acc;
  }
}

// ---------------- vectorized gather core ----------------
// Lane split: eg = lane>>4 (edge slot), cq = lane&15 (channel quad).
// Returns float4 acc valid in ALL lanes.

__device__ __forceinline__ float4 gather_row(const float* __restrict__ xw,
                                             const float* __restrict__ dinv,
                                             const int* __restrict__ cnt,
                                             const int2* __restrict__ bucket,
                                             const int4* __restrict__ ovf,
                                             const int* __restrict__ ovf_n,
                                             int node, int eg, int cq, float di) {
  int c = cnt[node];
  int cc = c < CAP ? c : CAP;
  const int2* bk = bucket + (size_t)node * CAP;
  float4 acc = make_float4(0.f, 0.f, 0.f, 0.f);

  int e0 = 0;
  for (; e0 + 8 <= cc; e0 += 8) {
    int2 Ea = bk[e0 + eg];
    int2 Eb = bk[e0 + 4 + eg];
    const float4 xa = *(const float4*)(xw + (size_t)Ea.x * 64 + cq * 4);
    const float4 xb = *(const float4*)(xw + (size_t)Eb.x * 64 + cq * 4);
    float va = dinv[Ea.x] * __int_as_float(Ea.y) * di;
    float vb = dinv[Eb.x] * __int_as_float(Eb.y) * di;
    acc.x = fmaf(xa.x, va, acc.x); acc.y = fmaf(xa.y, va, acc.y);
    acc.z = fmaf(xa.z, va, acc.z); acc.w = fmaf(xa.w, va, acc.w);
    acc.x = fmaf(xb.x, vb, acc.x); acc.y = fmaf(xb.y, vb, acc.y);
    acc.z = fmaf(xb.z, vb, acc.z); acc.w = fmaf(xb.w, vb, acc.w);
  }
  for (; e0 < cc; e0 += 4) {
    int e = e0 + eg;
    if (e < cc) {
      int2 E = bk[e];
      const float4 xa = *(const float4*)(xw + (size_t)E.x * 64 + cq * 4);
      float v = dinv[E.x] * __int_as_float(E.y) * di;
      acc.x = fmaf(xa.x, v, acc.x); acc.y = fmaf(xa.y, v, acc.y);
      acc.z = fmaf(xa.z, v, acc.z); acc.w = fmaf(xa.w, v, acc.w);
    }
  }
  acc.x += __shfl_xor(acc.x, 16, 64); acc.y += __shfl_xor(acc.y, 16, 64);
  acc.z += __shfl_xor(acc.z, 16, 64); acc.w += __shfl_xor(acc.w, 16, 64);
  acc.x += __shfl_xor(acc.x, 32, 64); acc.y += __shfl_xor(acc.y, 32, 64);
  acc.z += __shfl_xor(acc.z, 32, 64); acc.w += __shfl_xor(acc.w, 32, 64);

  if (c > CAP) {
    int on = ovf_n[0]; if (on > OVCAP) on = OVCAP;
    for (int t = 0; t < on; ++t) {
      int4 o = ovf[t];
      if (o.y == node) {
        const float4 xa = *(const float4*)(xw + (size_t)o.x * 64 + cq * 4);
        float v = dinv[o.x] * __int_as_float(o.z) * di;
        acc.x = fmaf(xa.x, v, acc.x); acc.y = fmaf(xa.y, v, acc.y);
        acc.z = fmaf(xa.z, v, acc.z); acc.w = fmaf(xa.w, v, acc.w);
      }
    }
  }
  const float4 xs = *(const float4*)(xw + (size_t)node * 64 + cq * 4);
  float dd = di * di;
  acc.x = fmaf(xs.x, dd, acc.x); acc.y = fmaf(xs.y, dd, acc.y);
  acc.z = fmaf(xs.z, dd, acc.z); acc.w = fmaf(xs.w, dd, acc.w);
  return acc;
}

// ---------------- layer-1 aggregation: gather + bias + ReLU ----------------

__global__ __launch_bounds__(256) void k_gather_l1(const float* __restrict__ xw,
                                                   const float* __restrict__ dinv,
                                                   const int* __restrict__ cnt,
                                                   const int2* __restrict__ bucket,
                                                   const int4* __restrict__ ovf,
                                                   const int* __restrict__ ovf_n,
                                                   const float* __restrict__ b,
                                                   float* __restrict__ h) {
  int lane = threadIdx.x & 63;
  int node = blockIdx.x * 4 + (threadIdx.x >> 6);
  if (node >= NN) return;
  int eg = lane >> 4, cq = lane & 15;
  float di = dinv[node];
  float4 acc = gather_row(xw, dinv, cnt, bucket, ovf, ovf_n, node, eg, cq, di);
  const float4 b4 = *(const float4*)(b + cq * 4);
  float4 r;
  r.x = fmaxf(acc.x + b4.x, 0.f); r.y = fmaxf(acc.y + b4.y, 0.f);
  r.z = fmaxf(acc.z + b4.z, 0.f); r.w = fmaxf(acc.w + b4.w, 0.f);
  if (lane < 16) *(float4*)(h + (size_t)node * 64 + cq * 4) = r;
}

// ---------------- layer-2 aggregation fused with both heads ----------------
// NO single-address atomic funnel here (R7 lesson: 25k same-address RMWs
// serialize at the coherence point, +224us drain tail).

__global__ __launch_bounds__(256) void k_gather_l2_heads(const float* __restrict__ xw,
                                                         const float* __restrict__ dinv,
                                                         const int* __restrict__ cnt,
                                                         const int2* __restrict__ bucket,
                                                         const int4* __restrict__ ovf,
                                                         const int* __restrict__ ovf_n,
                                                         const float* __restrict__ b2,
                                                         const float* __restrict__ Wn,
                                                         const float* __restrict__ bn,
                                                         const float* __restrict__ Wr,
                                                         const float* __restrict__ br,
                                                         float* __restrict__ logits,
                                                         float* __restrict__ rr) {
  int lane = threadIdx.x & 63;
  int node = blockIdx.x * 4 + (threadIdx.x >> 6);
  if (node >= NN) return;
  int eg = lane >> 4, cq = lane & 15;
  float di = dinv[node];
  float4 acc = gather_row(xw, dinv, cnt, bucket, ovf, ovf_n, node, eg, cq, di);
  const float4 b4 = *(const float4*)(b2 + cq * 4);
  float4 r;
  r.x = fmaxf(acc.x + b4.x, 0.f); r.y = fmaxf(acc.y + b4.y, 0.f);
  r.z = fmaxf(acc.z + b4.z, 0.f); r.w = fmaxf(acc.w + b4.w, 0.f);
  const float4 wn4 = *(const float4*)(Wn + cq * 4);
  const float4 wr4 = *(const float4*)(Wr + cq * 4);
  float an = r.x * wn4.x + r.y * wn4.y + r.z * wn4.z + r.w * wn4.w;
  float ar = r.x * wr4.x + r.y * wr4.y + r.z * wr4.z + r.w * wr4.w;
#pragma unroll
  for (int m = 8; m > 0; m >>= 1) {
    an += __shfl_xor(an, m, 64);
    ar += __shfl_xor(ar, m, 64);
  }
  if (lane == 0) {
    logits[node] = an + bn[0];
    float xr = ar + br[0];
    rr[node] = 0.01f / (1.0f + expf(-xr));
  }
}

// ---------------- softmax ----------------

#define RB 256  // reduction grid

__global__ __launch_bounds__(256) void k_smax_partial(const float* __restrict__ logits,
                                                      float* __restrict__ part) {
  __shared__ float s[256];
  float m = -INFINITY;
  for (int i = blockIdx.x * 256 + threadIdx.x; i < NN; i += RB * 256)
    m = fmaxf(m, logits[i]);
  s[threadIdx.x] = m;
  __syncthreads();
  for (int w = 128; w > 0; w >>= 1) {
    if (threadIdx.x < w) s[threadIdx.x] = fmaxf(s[threadIdx.x], s[threadIdx.x + w]);
    __syncthreads();
  }
  if (threadIdx.x == 0) part[blockIdx.x] = s[0];
}

__global__ __launch_bounds__(256) void k_smax_final(const float* __restrict__ part,
                                                    float* __restrict__ gmax) {
  __shared__ float s[256];
  s[threadIdx.x] = part[threadIdx.x];
  __syncthreads();
  for (int w = 128; w > 0; w >>= 1) {
    if (threadIdx.x < w) s[threadIdx.x] = fmaxf(s[threadIdx.x], s[threadIdx.x + w]);
    __syncthreads();
  }
  if (threadIdx.x == 0) gmax[0] = s[0];
}

// exp + block sums + 256-atomic global sum (256 funnel atomics ~ 4us, OK)
__global__ __launch_bounds__(256) void k_sexp(const float* __restrict__ logits,
                                              const float* __restrict__ gmax,
                                              float* __restrict__ sel,
                                              float* __restrict__ gsum) {
  __shared__ float s[256];
  float m = gmax[0];
  float acc = 0.0f;
  for (int i = blockIdx.x * 256 + threadIdx.x; i < NN; i += RB * 256) {
    float e = expf(logits[i] - m);
    sel[i] = e;
    acc += e;
  }
  s[threadIdx.x] = acc;
  __syncthreads();
  for (int w = 128; w > 0; w >>= 1) {
    if (threadIdx.x < w) s[threadIdx.x] += s[threadIdx.x + w];
    __syncthreads();
  }
  if (threadIdx.x == 0) unsafeAtomicAdd(gsum, s[0]);
}

__global__ __launch_bounds__(256) void k_snorm(float* __restrict__ sel,
                                               const float* __restrict__ gsum) {
  int i = blockIdx.x * 256 + threadIdx.x;
  if (i < NN) sel[i] *= (1.0f / gsum[0]);
}

// ---------------- launch ----------------

extern "C" void kernel_launch(void* const* d_in, const int* in_sizes, int n_in,
                              void* d_out, int out_size, void* d_ws, size_t ws_size,
                              hipStream_t stream) {
  const float* x  = (const float*)d_in[0];
  const int*   ei = (const int*)d_in[1];   // [2, E]: src row then dst row
  const float* ew = (const float*)d_in[2];
  const float* W1 = (const float*)d_in[3];
  const float* b1 = (const float*)d_in[4];
  const float* W2 = (const float*)d_in[5];
  const float* b2 = (const float*)d_in[6];
  const float* Wn = (const float*)d_in[7];
  const float* bn = (const float*)d_in[8];
  const float* Wr = (const float*)d_in[9];
  const float* br = (const float*)d_in[10];
  const int* src = ei;
  const int* dst = ei + NE;

  // ws layout — ALL float4/int2/int4 regions start at word offsets %4==0.
  float* ws = (float*)d_ws;
  float* xw      = ws;                                 // 6,400,000 words
  float* h       = xw + (size_t)NN * 64;               // 6,400,000
  float* dinv    = h + (size_t)NN * 64;                // 100,000
  float* logits  = dinv + NN;                          // 100,000
  int2*  bucket  = (int2*)(logits + NN);               // word 13,000,000 (%4==0) ✓
  int4*  ovf     = (int4*)(bucket + (size_t)NN * CAP); // word 19,400,000 (%4==0) ✓
  int*   cnt     = (int*)(ovf + OVCAP);                // 100,000
  int*   ovf_n   = cnt + NN;                           // 1
  float* gsum    = (float*)(ovf_n + 1);                // 1   (zeroed with cnt)
  float* part1   = gsum + 1;                           // 256
  float* gmax    = part1 + 256;                        // 1

  float* sel = (float*)d_out;                          // node_selector [N]
  float* rr  = (float*)d_out + NN;                     // rescue_ratios [N]

  int gN  = (NN + 255) / 256;
  int gN4 = NN / 4;  // NN % 4 == 0

  // zero cnt + ovf_n + gsum in one memset
  hipMemsetAsync(cnt, 0, (size_t)(NN + 2) * 4, stream);

  // ---- bucket build (XCD-partitioned) + GEMM1, co-scheduled ----
  k_bucket_gemm<<<NBUCK + NGEMM, 256, 0, stream>>>(src, dst, ew, cnt, bucket,
                                                   ovf, ovf_n, x, W1, xw);
  k_degsum<<<gN, 256, 0, stream>>>(cnt, bucket, ovf, ovf_n, dinv);

  // ---- layer 1 aggregation ----
  k_gather_l1<<<gN4, 256, 0, stream>>>(xw, dinv, cnt, bucket, ovf, ovf_n, b1, h);

  // ---- layer 2: gemm -> gather fused with heads ----
  k_gemm64<<<1024, 256, 0, stream>>>(h, W2, xw);
  k_gather_l2_heads<<<gN4, 256, 0, stream>>>(xw, dinv, cnt, bucket, ovf, ovf_n,
                                             b2, Wn, bn, Wr, br, logits, rr);

  // ---- softmax ----
  k_smax_partial<<<RB, 256, 0, stream>>>(logits, part1);
  k_smax_final<<<1, 256, 0, stream>>>(part1, gmax);
  k_sexp<<<RB, 256, 0, stream>>>(logits, gmax, sel, gsum);
  k_snorm<<<gN, 256, 0, stream>>>(sel, gsum);
}